// Round 1
// baseline (104.787 us; speedup 1.0000x reference)
//
#include <hip/hip_runtime.h>
#include <stdint.h>

typedef _Float16 half8 __attribute__((ext_vector_type(8)));
typedef _Float16 half2_ __attribute__((ext_vector_type(2)));
typedef float f32x4 __attribute__((ext_vector_type(4)));

#define N_ 32
#define C_ 8
#define W_ 65536
#define F_ 16
#define WW_ 64
#define OW_ 65473
#define K_ 512

// funnel16(hi, lo) = (hi << 16) | (lo >> 16)  -> v_alignbit_b32
__device__ __forceinline__ uint32_t funnel16(uint32_t hi, uint32_t lo) {
  return (uint32_t)((((uint64_t)hi << 32) | (uint64_t)lo) >> 16);
}

// x-tile LDS swizzle: XOR 16B-chunk index to break (c15+g) mod-8 aliasing
__device__ __forceinline__ uint32_t xswz(uint32_t byteoff) {
  uint32_t ch = byteoff >> 4;
  ch ^= (ch >> 3) & 7u;
  return (byteoff & 15u) | (ch << 4);
}

__global__ __launch_bounds__(256, 2)
void corr1d_mfma(const float* __restrict__ x, const float* __restrict__ w,
                 const float* __restrict__ b, float* __restrict__ out) {
  // 32 KB: first 9216 B used as fp16 x-tile (K-loop), whole buffer reused as
  // fp32 transpose staging in the epilogue (after a barrier).
  __shared__ __align__(16) float smemf[4 * 2048];
  uint8_t* xs_bytes = reinterpret_cast<uint8_t*>(smemf);

  const int tid = threadIdx.x;
  const int n   = blockIdx.x >> 7;   // 32 n
  const int tt  = blockIdx.x & 127;  // 128 t-tiles of 512
  const int t0  = tt << 9;

  // ---- stage x tile: 8 channels x 576 fp16 elems (swizzled chunks) ----
  const float* xn = x + (size_t)n * (C_ * W_);
  for (int u = tid; u < 2304; u += 256) {   // 2304 = 8 * 288 dword units
    int c = u / 288;
    int p = (u - c * 288) * 2;              // element offset 0..574 (even)
    int gi = t0 + p;
    float v0 = (gi     < W_) ? xn[c * W_ + gi]     : 0.0f;
    float v1 = (gi + 1 < W_) ? xn[c * W_ + gi + 1] : 0.0f;
    half2_ hv; hv[0] = (_Float16)v0; hv[1] = (_Float16)v1;
    uint32_t boff = (uint32_t)(c * 576 + p) * 2u;
    *reinterpret_cast<half2_*>(xs_bytes + xswz(boff)) = hv;
  }

  // ---- w fragments straight from global into registers ----
  // w global layout [f][c][j] == [f][k] with k = c*64+j (our k-order).
  // A frag (16x32, row = lane&15): lane elements k = 32*s + 8*(lane>>4) + e.
  const int lane = tid & 63;
  const int c15  = lane & 15;
  const int g    = lane >> 4;
  half8 wf[16];
  const float* wrow = w + c15 * K_;
  #pragma unroll
  for (int s = 0; s < 16; ++s) {
    const float* pw = wrow + 32 * s + 8 * g;
    f32x4 wa = *reinterpret_cast<const f32x4*>(pw);
    f32x4 wb = *reinterpret_cast<const f32x4*>(pw + 4);
    half8 h;
    h[0]=(_Float16)wa[0]; h[1]=(_Float16)wa[1]; h[2]=(_Float16)wa[2]; h[3]=(_Float16)wa[3];
    h[4]=(_Float16)wb[0]; h[5]=(_Float16)wb[1]; h[6]=(_Float16)wb[2]; h[7]=(_Float16)wb[3];
    wf[s] = h;
  }

  __syncthreads();

  const int wv  = tid >> 6;   // wave 0..3
  const int tlw = wv << 7;    // wave's 128-col slice

  f32x4 acc[8];
  #pragma unroll
  for (int r = 0; r < 8; ++r) acc[r] = (f32x4){0.f, 0.f, 0.f, 0.f};

  union Win { half8 h[2]; uint32_t d[8]; };

  // ---- K loop: 16 k-steps of 32; tile r cols are t = t0+tlw+r+8*col ----
  #pragma unroll
  for (int s = 0; s < 16; ++s) {
    const int c  = s >> 1;
    const int jb = (s & 1) * 32;
    const int A0 = tlw + 8 * c15 + jb + 8 * g;   // multiple of 8 -> 16B aligned
    uint32_t boff = (uint32_t)(c * 576 + A0) * 2u;
    Win win;
    win.h[0] = *reinterpret_cast<const half8*>(xs_bytes + xswz(boff));
    win.h[1] = *reinterpret_cast<const half8*>(xs_bytes + xswz(boff + 16));
    #pragma unroll
    for (int r = 0; r < 8; ++r) {
      union { uint32_t d[4]; half8 h; } fr;
      const int m = r >> 1;
      if ((r & 1) == 0) {
        fr.d[0] = win.d[m];     fr.d[1] = win.d[m + 1];
        fr.d[2] = win.d[m + 2]; fr.d[3] = win.d[m + 3];
      } else {
        fr.d[0] = funnel16(win.d[m + 1], win.d[m]);
        fr.d[1] = funnel16(win.d[m + 2], win.d[m + 1]);
        fr.d[2] = funnel16(win.d[m + 3], win.d[m + 2]);
        fr.d[3] = funnel16(win.d[m + 4], win.d[m + 3]);
      }
      acc[r] = __builtin_amdgcn_mfma_f32_16x16x32_f16(wf[s], fr.h, acc[r], 0, 0, 0);
    }
  }

  __syncthreads();  // done reading x-tile; reuse LDS for transpose

  // ---- epilogue: accs -> per-wave LDS (swizzled) -> coalesced stores ----
  // C/D layout: col = lane&15 (t-col), row f = 4*(lane>>4) + q.
  float* obw = smemf + wv * 2048;   // 128 t x 16 f
  #pragma unroll
  for (int r = 0; r < 8; ++r) {
    const int tl = r + 8 * c15;     // wave-local t 0..127
    #pragma unroll
    for (int q = 0; q < 4; ++q) {
      const int f = 4 * g + q;
      obw[tl * 16 + (f ^ (tl & 15))] = acc[r][q];
    }
  }
  __syncthreads();

  const int tbase = t0 + tlw;
  #pragma unroll
  for (int f = 0; f < 16; ++f) {
    const float addb = 8.0f * b[f];   // reference adds bias C times
    float* orow = out + ((size_t)n * F_ + f) * OW_;
    #pragma unroll
    for (int seg = 0; seg < 2; ++seg) {
      const int tl = seg * 64 + lane;
      const int tg = tbase + tl;
      float v = obw[tl * 16 + (f ^ (tl & 15))] + addb;
      if (tg < OW_) orow[tg] = v;
    }
  }
}

extern "C" void kernel_launch(void* const* d_in, const int* in_sizes, int n_in,
                              void* d_out, int out_size, void* d_ws, size_t ws_size,
                              hipStream_t stream) {
  (void)in_sizes; (void)n_in; (void)out_size; (void)d_ws; (void)ws_size;
  const float* x = (const float*)d_in[0];
  const float* w = (const float*)d_in[1];
  const float* b = (const float*)d_in[2];
  float* out = (float*)d_out;
  corr1d_mfma<<<dim3(32 * 128), dim3(256), 0, stream>>>(x, w, b, out);
}

// Round 2
// 59.210 us; speedup vs baseline: 1.7698x; 1.7698x over previous
//
#include <hip/hip_runtime.h>
#include <stdint.h>

typedef _Float16 half8 __attribute__((ext_vector_type(8)));
typedef _Float16 half4_t __attribute__((ext_vector_type(4)));
typedef float f32x4 __attribute__((ext_vector_type(4)));

#define N_ 32
#define C_ 8
#define W_ 65536
#define F_ 16
#define OW_ 65473
#define K_ 512
#define TILE_T 512
#define NTILES 4
#define XS 640                 // halfs per channel row in an x buffer
#define XBUF_HALFS (C_ * XS)   // 5120
#define WL_HALFS (F_ * K_)     // 8192

// funnel16(hi, lo) = (hi:lo) >> 16  -> v_alignbit_b32
__device__ __forceinline__ uint32_t funnel16(uint32_t hi, uint32_t lo) {
  return (uint32_t)((((uint64_t)hi << 32) | (uint64_t)lo) >> 16);
}

// w LDS swizzle: XOR the 16B-chunk index low bits with c15 (ch>>6) to break
// the "all c15 lanes hit the same bank group" pattern of the [f][k] layout.
__device__ __forceinline__ uint32_t wswz(uint32_t e /* half index, mult of 4 */) {
  uint32_t ch = e >> 3;
  ch ^= (ch >> 6) & 7u;
  return (ch << 4) | ((e & 7u) << 1);
}

__global__ __launch_bounds__(256, 4)
void corr1d_mfma(const float* __restrict__ x, const float* __restrict__ w,
                 const float* __restrict__ b, float* __restrict__ out) {
  __shared__ __align__(16) _Float16 wl[WL_HALFS];      // 16 KB
  __shared__ __align__(16) _Float16 xb[2][XBUF_HALFS]; // 2 x 10 KB

  const int tid = threadIdx.x;
  const int n   = blockIdx.x >> 5;        // 32 n
  const int tb0 = (blockIdx.x & 31) << 11; // 32 t-blocks of 2048

  const int lane = tid & 63;
  const int c15  = lane & 15;
  const int g    = lane >> 4;
  const int wv   = tid >> 6;
  const int tlw  = wv << 7;               // wave's 128-col slice within tile

  const float* xn = x + (size_t)n * (C_ * W_);

  // ---- prologue: stage w (16x512 f32 -> f16, swizzled), once per block ----
  #pragma unroll
  for (int j = 0; j < 8; ++j) {
    int e = (tid + 256 * j) * 4;
    f32x4 v = *reinterpret_cast<const f32x4*>(w + e);
    half4_t h; h[0] = (_Float16)v[0]; h[1] = (_Float16)v[1];
    h[2] = (_Float16)v[2]; h[3] = (_Float16)v[3];
    *reinterpret_cast<half4_t*>(reinterpret_cast<char*>(wl) + wswz((uint32_t)e)) = h;
  }

  // ---- stage x tile 0 ----
  {
    f32x4 xr[5];
    #pragma unroll
    for (int j = 0; j < 5; ++j) {
      int u = tid + 256 * j;
      int c = u / 160;
      int p = (u - c * 160) * 4;
      int gi = tb0 + p;
      if (gi < W_) xr[j] = *reinterpret_cast<const f32x4*>(xn + c * W_ + gi);
      else         xr[j] = (f32x4){0.f, 0.f, 0.f, 0.f};
    }
    #pragma unroll
    for (int j = 0; j < 5; ++j) {
      int u = tid + 256 * j;
      int c = u / 160;
      int p = (u - c * 160) * 4;
      half4_t h; h[0] = (_Float16)xr[j][0]; h[1] = (_Float16)xr[j][1];
      h[2] = (_Float16)xr[j][2]; h[3] = (_Float16)xr[j][3];
      *reinterpret_cast<half4_t*>(&xb[0][c * XS + p]) = h;
    }
  }

  const f32x4 bv4 = *reinterpret_cast<const f32x4*>(b + 4 * g);

  __syncthreads();

  int buf = 0;
  union Win { half8 h[2]; uint32_t d[8]; };

  for (int i = 0; i < NTILES; ++i) {
    const bool pf = (i + 1 < NTILES);

    // T14 issue-early: next tile's global loads in flight during compute
    f32x4 xr[5];
    if (pf) {
      const int gt0 = tb0 + (i + 1) * TILE_T;
      #pragma unroll
      for (int j = 0; j < 5; ++j) {
        int u = tid + 256 * j;
        int c = u / 160;
        int p = (u - c * 160) * 4;
        int gi = gt0 + p;
        if (gi < W_) xr[j] = *reinterpret_cast<const f32x4*>(xn + c * W_ + gi);
        else         xr[j] = (f32x4){0.f, 0.f, 0.f, 0.f};
      }
    }

    f32x4 acc[8];
    #pragma unroll
    for (int r = 0; r < 8; ++r) acc[r] = (f32x4){0.f, 0.f, 0.f, 0.f};

    const _Float16* xcur = xb[buf];
    #pragma unroll
    for (int s = 0; s < 16; ++s) {
      // A frag: w row c15, k = 32s + 8g + e  (same k-order as B -> cancels)
      const uint32_t we = (uint32_t)(c15 * K_ + 32 * s + 8 * g);
      const half8 wf = *reinterpret_cast<const half8*>(
                           reinterpret_cast<const char*>(wl) + wswz(we));
      const int c  = s >> 1;
      const int jb = (s & 1) * 32;
      const int A0 = tlw + 8 * c15 + jb + 8 * g;  // mult of 8 -> 16B aligned
      Win win;
      win.h[0] = *reinterpret_cast<const half8*>(xcur + c * XS + A0);
      win.h[1] = *reinterpret_cast<const half8*>(xcur + c * XS + A0 + 8);
      #pragma unroll
      for (int r = 0; r < 8; ++r) {
        union { uint32_t d[4]; half8 h; } fr;
        const int m = r >> 1;
        if ((r & 1) == 0) {
          fr.d[0] = win.d[m];     fr.d[1] = win.d[m + 1];
          fr.d[2] = win.d[m + 2]; fr.d[3] = win.d[m + 3];
        } else {
          fr.d[0] = funnel16(win.d[m + 1], win.d[m]);
          fr.d[1] = funnel16(win.d[m + 2], win.d[m + 1]);
          fr.d[2] = funnel16(win.d[m + 3], win.d[m + 2]);
          fr.d[3] = funnel16(win.d[m + 4], win.d[m + 3]);
        }
        acc[r] = __builtin_amdgcn_mfma_f32_16x16x32_f16(wf, fr.h, acc[r], 0, 0, 0);
      }
    }

    // write-late: stage next tile into the other buffer
    if (pf) {
      #pragma unroll
      for (int j = 0; j < 5; ++j) {
        int u = tid + 256 * j;
        int c = u / 160;
        int p = (u - c * 160) * 4;
        half4_t h; h[0] = (_Float16)xr[j][0]; h[1] = (_Float16)xr[j][1];
        h[2] = (_Float16)xr[j][2]; h[3] = (_Float16)xr[j][3];
        *reinterpret_cast<half4_t*>(&xb[buf ^ 1][c * XS + p]) = h;
      }
    }

    __syncthreads();

    // ---- register-transpose epilogue (after barrier: store drain overlaps
    // next tile's work). lane holds t-run [tl0, tl0+8) for f = 4g+q. ----
    const int tl0 = tb0 + i * TILE_T + tlw + 8 * c15;
    #pragma unroll
    for (int q = 0; q < 4; ++q) {
      const int f = 4 * g + q;
      const float bias = 8.0f * bv4[q];   // reference adds bias C times
      f32x4 sa = { acc[0][q] + bias, acc[1][q] + bias,
                   acc[2][q] + bias, acc[3][q] + bias };
      f32x4 sb = { acc[4][q] + bias, acc[5][q] + bias,
                   acc[6][q] + bias, acc[7][q] + bias };
      float* row = out + (size_t)(n * F_ + f) * OW_ + tl0;
      if (tl0 + 8 <= OW_) {
        __builtin_memcpy(row,     &sa, 16);   // rows are 4B-aligned only (OW odd)
        __builtin_memcpy(row + 4, &sb, 16);
      } else {
        #pragma unroll
        for (int jj = 0; jj < 8; ++jj) {
          if (tl0 + jj < OW_) row[jj] = (jj < 4) ? sa[jj] : sb[jj - 4];
        }
      }
    }

    buf ^= 1;
  }
}

extern "C" void kernel_launch(void* const* d_in, const int* in_sizes, int n_in,
                              void* d_out, int out_size, void* d_ws, size_t ws_size,
                              hipStream_t stream) {
  (void)in_sizes; (void)n_in; (void)out_size; (void)d_ws; (void)ws_size;
  const float* x = (const float*)d_in[0];
  const float* w = (const float*)d_in[1];
  const float* b = (const float*)d_in[2];
  float* out = (float*)d_out;
  corr1d_mfma<<<dim3(32 * 32), dim3(256), 0, stream>>>(x, w, b, out);
}